// Round 8
// baseline (1322.656 us; speedup 1.0000x reference)
//
#include <hip/hip_runtime.h>
#include <math.h>

typedef __attribute__((ext_vector_type(8))) short short8;
typedef __attribute__((ext_vector_type(4))) float f32x4;

#define EPI_QKV   0
#define EPI_PEXP  1
#define EPI_R     2
#define EPI_Z     3
#define EPI_N     4

__device__ __forceinline__ unsigned short f2bf(float f) {
    unsigned int u = __float_as_uint(f);
    u += 0x7fffu + ((u >> 16) & 1u);
    return (unsigned short)(u >> 16);
}
__device__ __forceinline__ float bf2f(unsigned short s) {
    return __uint_as_float(((unsigned int)s) << 16);
}

struct alignas(8) us4 { unsigned short a, b, c, d; };

#define GLD_LDS16(gp, lp) \
    __builtin_amdgcn_global_load_lds((const __attribute__((address_space(1))) unsigned int*)(gp), \
                                     (__attribute__((address_space(3))) unsigned int*)(lp), 16, 0, 0)

#define BAR   do { asm volatile("" ::: "memory"); __builtin_amdgcn_s_barrier(); \
                   asm volatile("" ::: "memory"); } while (0)
#define VMC6  asm volatile("s_waitcnt vmcnt(6)" ::: "memory")
#define VMC4  asm volatile("s_waitcnt vmcnt(4)" ::: "memory")
#define VMC2  asm volatile("s_waitcnt vmcnt(2)" ::: "memory")
#define VMC0  asm volatile("s_waitcnt vmcnt(0)" ::: "memory")

// ============================================================================
// 256x256 tile, BK=64, 512 threads (8 waves: 2M x 4N).
// One-phase-ahead register pipeline; READ-ALIGNED staging slots:
//   A0 slot = rows {0-63,128-191}   (all rows a0=LDA(MH=0) reads)
//   A1 slot = rows {64-127,192-255} (a1)
//   B0 slot = rows {q*64+0..31,  q=0..3} (all rows b0=LDB(BH=0) reads)
//   B1 slot = rows {q*64+32..63, q=0..3} (b1)
// B slots staged with interleaved row map SBROW(w)=(w>>2)*64+(w&3)*8
// (8 consecutive rows per wave -> coalescing and row&7 swizzle key intact);
// LDB reads slot-local row wc*32+nf*16+lr.
// Schedule per K-tile t (gate BEFORE barrier; stage AFTER gate):
//   ph0: VMC2|VMC0(last); BAR; read b1(t);   stage B0(t+1); MMA q00(a0,b0)
//   ph1:                  BAR; read a1(t);   stage A1(t+1); MMA q01(a0,b1)
//   ph2: VMC4;            BAR; read a0(t+1); stage B1(t+1); MMA q10(a1,b0)
//   ph3: VMC4;            BAR; read b0(t+1); stage A0(t+2); MMA q11(a1,b1)
// FIFO proof (steady state, queue at each gate):
//   ph0 VMC2: [SA1(t),SB1(t),SA0(t+1)] -> retires SA1(t),SB1(t); b1(t) OK
//   ph2 VMC4: [SA0(t+1),SB0(t+1),SA1(t+1)] -> retires SA0(t+1); a0(t+1) OK
//   ph3 VMC4: [SB0(t+1),SA1(t+1),SB1(t+1)] -> retires SB0(t+1); b0(t+1) OK
// Every MFMA cluster consumes ds_reads issued >=1 phase earlier; each phase's
// ds_reads write regs not sourced by that phase's MFMA. 4 barriers/K-tile.
// LDS 128 KiB, XOR-swizzle byte^=(row&7)<<4 via inverse-swizzled global src.
// ============================================================================
template<int EPI, int SWZ>
__global__ void __launch_bounds__(512, 2)
gemm256(const unsigned short* __restrict__ A, long long sAb, int lda,
        const unsigned short* __restrict__ Bt, long long sBb, int ldb,
        const float* __restrict__ bias,
        void* __restrict__ C, long long sCb, int ldc,
        int K, float scale,
        const float* __restrict__ hptr,
        const unsigned short* __restrict__ updptr,
        float* __restrict__ psum,
        unsigned short* __restrict__ vt)
{
    extern __shared__ char smem[];   // 131072 B

    const int z = blockIdx.z;
    A  += (size_t)z * (size_t)sAb;
    Bt += (size_t)z * (size_t)sBb;

    int bx, by;
    if (SWZ) {
        const int bid = blockIdx.y * 8 + blockIdx.x;   // grid (8,128)
        const int xcd = bid & 7, i = bid >> 3;
        bx = i & 7;
        by = (xcd << 4) | (i >> 3);
    } else {
        bx = blockIdx.x; by = blockIdx.y;
    }
    const int m0 = by * 256;
    const int n0 = bx * 256;

    const int tid = threadIdx.x;
    const int w  = tid >> 6;      // wave 0..7
    const int l  = tid & 63;
    const int wr = w >> 2;        // 0..1 (M half: 128 rows)
    const int wc = w & 3;         // 0..3 (N quarter: 64 cols)
    const int lr = l & 15;
    const int lg = l >> 4;
    const int rs = (lr & 7) << 4; // read-side XOR swizzle

    const int srw = l >> 3;                        // staging row-within-8
    const int scb = ((l & 7) << 4) ^ (srw << 4);   // inverse-swizzled src col byte
    const int sbrow = ((w >> 2) << 6) + ((w & 3) << 3);  // interleaved B row base

    const long long ldab = (long long)lda * 2;
    const long long ldbb = (long long)ldb * 2;

    f32x4 acc[2][4][4] = {};
    short8 a0[4][2], a1[4][2], b0[2][2], b1[2][2];

#define STAGE1(gbase, ldbytes, grow0, ldsoff) { \
    const char* g_ = (const char*)(gbase) + \
        (size_t)((grow0) + w*8 + srw) * (ldbytes) + scb; \
    GLD_LDS16(g_, smem + (ldsoff) + (w << 10)); }

#define STAGE1B(gbase, grow0, ldsoff) { \
    const char* g_ = (const char*)(gbase) + \
        (size_t)((grow0) + sbrow + srw) * ldbb + scb; \
    GLD_LDS16(g_, smem + (ldsoff) + (w << 10)); }

#define AOFF(buf) ((buf)*65536)
#define BOFF(buf) ((buf)*65536 + 32768)

// stage slots (2 gload_lds per thread each)
#define SA0(buf, base) { STAGE1(base, ldab, m0 + 0,   AOFF(buf) + 0); \
                         STAGE1(base, ldab, m0 + 128, AOFF(buf) + 16384); }
#define SA1(buf, base) { STAGE1(base, ldab, m0 + 64,  AOFF(buf) + 8192); \
                         STAGE1(base, ldab, m0 + 192, AOFF(buf) + 24576); }
// B0 slot: global rows {0-31,64-95} then {128-159,192-223}  (16 KiB at BOFF+0)
#define SB0(buf, base) { STAGE1B(base, n0 + 0,   BOFF(buf) + 0); \
                         STAGE1B(base, n0 + 128, BOFF(buf) + 8192); }
// B1 slot: global rows {32-63,96-127} then {160-191,224-255} (16 KiB at BOFF+16384)
#define SB1(buf, base) { STAGE1B(base, n0 + 32,  BOFF(buf) + 16384); \
                         STAGE1B(base, n0 + 160, BOFF(buf) + 24576); }

// register loads (8 / 4 x ds_read_b128)
#define LDA(dst, MH, buf) { \
    const char* Ab_ = smem + AOFF(buf); \
    _Pragma("unroll") \
    for (int mf = 0; mf < 4; ++mf) { \
        const int row_ = wr*128 + (MH)*64 + mf*16 + lr; \
        _Pragma("unroll") \
        for (int kk = 0; kk < 2; ++kk) \
            dst[mf][kk] = *(const short8*)(Ab_ + row_*128 + ((kk*64 + lg*16) ^ rs)); } }

// slot-local row = wc*32 + nf*16 + lr  (slot holds exactly the BH rows)
#define LDB(dst, BH, buf) { \
    const char* Bb_ = smem + BOFF(buf) + (BH)*16384; \
    _Pragma("unroll") \
    for (int nf = 0; nf < 2; ++nf) { \
        const int row_ = wc*32 + nf*16 + lr; \
        _Pragma("unroll") \
        for (int kk = 0; kk < 2; ++kk) \
            dst[nf][kk] = *(const short8*)(Bb_ + row_*128 + ((kk*64 + lg*16) ^ rs)); } }

// one C-quadrant x K=64: 16 MFMA, kk outer (dep distance 8)
#define MMA(MH, BH, av, bv) { \
    __builtin_amdgcn_s_setprio(1); \
    _Pragma("unroll") \
    for (int kk = 0; kk < 2; ++kk) \
    _Pragma("unroll") \
    for (int mf = 0; mf < 4; ++mf) \
    _Pragma("unroll") \
    for (int nf = 0; nf < 2; ++nf) \
        acc[MH][mf][(BH)*2+nf] = __builtin_amdgcn_mfma_f32_16x16x32_bf16( \
            av[mf][kk], bv[nf][kk], acc[MH][mf][(BH)*2+nf], 0, 0, 0); \
    __builtin_amdgcn_s_setprio(0); }

    // prologue: tile0 full + A0(1); retire A0(0),B0(0); preload a0(0), b0(0)
    SA0(0, A); SB0(0, Bt); SA1(0, A); SB1(0, Bt);
    SA0(1, A + 64);
    VMC6;                          // 10 outstanding -> retire SA0(0),SB0(0)
    BAR;
    LDA(a0, 0, 0);
    LDB(b0, 0, 0);

    const int NT = K >> 6;
    for (int t = 0; t < NT; ++t) {
        const int p = t & 1, q = p ^ 1;
        const bool s1 = (t + 1 < NT), s2 = (t + 2 < NT);
        const unsigned short* Anx = A  + (size_t)(t + 1) * 64;
        const unsigned short* Bnx = Bt + (size_t)(t + 1) * 64;
        const unsigned short* Anx2 = A + (size_t)(t + 2) * 64;

        // ph0: retire SA1(t),SB1(t) (tail: all), read b1(t), stage B0(t+1)
        if (t == NT - 1) { VMC0; } else { VMC2; }
        BAR;
        LDB(b1, 1, p);
        if (s1) { SB0(q, Bnx); }
        MMA(0, 0, a0, b0);
        // ph1: read a1(t), stage A1(t+1)
        BAR;
        LDA(a1, 1, p);
        if (s1) { SA1(q, Anx); }
        MMA(0, 1, a0, b1);
        // ph2: retire SA0(t+1), read a0(t+1), stage B1(t+1)
        VMC4;
        BAR;
        if (s1) { LDA(a0, 0, q); }
        if (s1) { SB1(q, Bnx); }
        MMA(1, 0, a1, b0);
        // ph3: retire SB0(t+1), read b0(t+1), stage A0(t+2)
        VMC4;
        BAR;
        if (s1) { LDB(b0, 0, q); }
        if (s2) { SA0(p, Anx2); }
        MMA(1, 1, a1, b1);
    }

    // ======================= epilogues =======================
    const int Mb = gridDim.y << 8;          // rows per batch slab
    const size_t zc = (size_t)z * (size_t)sCb;

    if (EPI == EPI_PEXP) {
        float psl[2][4][4];
        #pragma unroll
        for (int mh = 0; mh < 2; ++mh)
            #pragma unroll
            for (int mf = 0; mf < 4; ++mf)
                #pragma unroll
                for (int r = 0; r < 4; ++r) psl[mh][mf][r] = 0.0f;

        #pragma unroll
        for (int mh = 0; mh < 2; ++mh)
        #pragma unroll
        for (int mf = 0; mf < 4; ++mf)
        #pragma unroll
        for (int nf = 0; nf < 4; ++nf) {
            const int col = n0 + wc * 64 + nf * 16 + lr;
            #pragma unroll
            for (int r = 0; r < 4; ++r) {
                const int row = m0 + wr * 128 + mh * 64 + mf * 16 + lg * 4 + r;
                const float e = __expf(acc[mh][mf][nf][r] * scale);
                ((unsigned short*)C)[zc + (size_t)row * ldc + col] = f2bf(e);
                psl[mh][mf][r] += e;
            }
        }
        #pragma unroll
        for (int d = 1; d < 16; d <<= 1)
            #pragma unroll
            for (int mh = 0; mh < 2; ++mh)
                #pragma unroll
                for (int mf = 0; mf < 4; ++mf)
                    #pragma unroll
                    for (int r = 0; r < 4; ++r)
                        psl[mh][mf][r] += __shfl_xor(psl[mh][mf][r], d);
        __syncthreads();
        float* red = (float*)smem;             // [4 waves][256 rows]
        if (lr == 0) {
            #pragma unroll
            for (int mh = 0; mh < 2; ++mh)
                #pragma unroll
                for (int mf = 0; mf < 4; ++mf)
                    #pragma unroll
                    for (int r = 0; r < 4; ++r)
                        red[wc * 256 + wr * 128 + mh * 64 + mf * 16 + lg * 4 + r]
                            = psl[mh][mf][r];
        }
        __syncthreads();
        if (tid < 256) {
            const float sres = red[tid] + red[256 + tid] + red[512 + tid] + red[768 + tid];
            psum[(size_t)bx * 32768 + (size_t)z * 512 + m0 + tid] = sres;
        }
        return;
    }

    float invs[2][4][4];
    if (EPI == EPI_R || EPI == EPI_Z || EPI == EPI_N) {
        #pragma unroll
        for (int mh = 0; mh < 2; ++mh)
            #pragma unroll
            for (int mf = 0; mf < 4; ++mf)
                #pragma unroll
                for (int r = 0; r < 4; ++r) {
                    const int row = m0 + wr * 128 + mh * 64 + mf * 16 + lg * 4 + r;
                    const size_t gr = (size_t)z * 512 + row;
                    invs[mh][mf][r] = 1.0f / (psum[gr] + psum[32768 + gr]);
                }
    }

    #pragma unroll
    for (int mh = 0; mh < 2; ++mh) {
        #pragma unroll
        for (int mf = 0; mf < 4; ++mf) {
            #pragma unroll
            for (int nf = 0; nf < 4; ++nf) {
                const int col = n0 + wc * 64 + nf * 16 + lr;
                const float bval = (EPI == EPI_QKV) ? bias[col] : 0.0f;
                if (EPI == EPI_QKV && bx >= 4) {
                    const int row0 = m0 + wr * 128 + mh * 64 + mf * 16 + lg * 4;
                    us4 o = { f2bf(acc[mh][mf][nf][0] + bval),
                              f2bf(acc[mh][mf][nf][1] + bval),
                              f2bf(acc[mh][mf][nf][2] + bval),
                              f2bf(acc[mh][mf][nf][3] + bval) };
                    *(us4*)(vt + (size_t)(row0 >> 9) * 524288 +
                            (size_t)(col - 1024) * 512 + (row0 & 511)) = o;
                } else {
                    #pragma unroll
                    for (int r = 0; r < 4; ++r) {
                        const int row = m0 + wr * 128 + mh * 64 + mf * 16 + lg * 4 + r;
                        float v = acc[mh][mf][nf][r] + bval;
                        if (EPI == EPI_QKV) {
                            ((unsigned short*)C)[(size_t)row * ldc + col] = f2bf(v);
                        } else if (EPI == EPI_R) {
                            v *= invs[mh][mf][r];
                            const size_t flat = (size_t)z * Mb + row;
                            const float hh = hptr[flat * 1024 + col];
                            const float sg = 1.0f / (1.0f + __expf(-v));
                            ((unsigned short*)C)[flat * 2048 + 1024 + col] = f2bf(hh * sg);
                        } else if (EPI == EPI_Z) {
                            v *= invs[mh][mf][r];
                            const size_t flat = (size_t)z * Mb + row;
                            const float sg = 1.0f / (1.0f + __expf(-v));
                            ((unsigned short*)C)[flat * 1024 + col] = f2bf(sg);
                        } else { // EPI_N
                            v *= invs[mh][mf][r];
                            const size_t flat = (size_t)z * Mb + row;
                            const float u  = bf2f(updptr[flat * 1024 + col]);
                            const float hh = hptr[flat * 1024 + col];
                            ((float*)C)[flat * 1024 + col] = (1.0f - u) * hh + u * tanhf(v);
                        }
                    }
                }
            }
        }
    }
#undef STAGE1
#undef STAGE1B
#undef AOFF
#undef BOFF
#undef SA0
#undef SA1
#undef SB0
#undef SB1
#undef LDA
#undef LDB
#undef MMA
}

// ============================================================================
// memory-bound helper kernels
// ============================================================================

__global__ void __launch_bounds__(256)
prep_xh(const float* __restrict__ x, const float* __restrict__ h, unsigned short* __restrict__ xh)
{
    const size_t t = (size_t)blockIdx.x * 256 + threadIdx.x;
    const size_t f = t * 4;
    const size_t row = f >> 10, col = f & 1023;
    const float4 vx = *(const float4*)(x + f);
    const float4 vh = *(const float4*)(h + f);
    us4 ox = { f2bf(vx.x), f2bf(vx.y), f2bf(vx.z), f2bf(vx.w) };
    us4 oh = { f2bf(vh.x), f2bf(vh.y), f2bf(vh.z), f2bf(vh.w) };
    *(us4*)(xh + row * 2048 + col)        = ox;
    *(us4*)(xh + row * 2048 + 1024 + col) = oh;
}

__global__ void __launch_bounds__(256)
transpose_w(const float* __restrict__ W, unsigned short* __restrict__ WT, int N)
{
    __shared__ float t[32][33];
    const int k0 = blockIdx.y * 32, n0 = blockIdx.x * 32;
    const int tx = threadIdx.x & 31, ty = threadIdx.x >> 5;
    #pragma unroll
    for (int i = 0; i < 4; ++i)
        t[ty + i * 8][tx] = W[(size_t)(k0 + ty + i * 8) * N + n0 + tx];
    __syncthreads();
    #pragma unroll
    for (int i = 0; i < 4; ++i)
        WT[(size_t)(n0 + ty + i * 8) * 2048 + k0 + tx] = f2bf(t[tx][ty + i * 8]);
}

__global__ void __launch_bounds__(256)
layernorm1024(float* __restrict__ Y, const float* __restrict__ gamma, const float* __restrict__ beta)
{
    const int row = blockIdx.x * 4 + (threadIdx.x >> 6);
    const int l = threadIdx.x & 63;
    float* p = Y + (size_t)row * 1024;
    float4 v[4];
    float s = 0.0f, s2 = 0.0f;
    #pragma unroll
    for (int i = 0; i < 4; ++i) {
        v[i] = ((const float4*)p)[i * 64 + l];
        s  += v[i].x + v[i].y + v[i].z + v[i].w;
        s2 += v[i].x * v[i].x + v[i].y * v[i].y + v[i].z * v[i].z + v[i].w * v[i].w;
    }
    #pragma unroll
    for (int d = 32; d; d >>= 1) { s += __shfl_xor(s, d); s2 += __shfl_xor(s2, d); }
    const float mu = s * (1.0f / 1024.0f);
    const float var = s2 * (1.0f / 1024.0f) - mu * mu;
    const float inv = rsqrtf(var + 1e-5f);
    #pragma unroll
    for (int i = 0; i < 4; ++i) {
        const float4 gv = ((const float4*)gamma)[i * 64 + l];
        const float4 bv = ((const float4*)beta)[i * 64 + l];
        float4 o;
        o.x = (v[i].x - mu) * inv * gv.x + bv.x;
        o.y = (v[i].y - mu) * inv * gv.y + bv.y;
        o.z = (v[i].z - mu) * inv * gv.z + bv.z;
        o.w = (v[i].w - mu) * inv * gv.w + bv.w;
        ((float4*)p)[i * 64 + l] = o;
    }
}

__global__ void __launch_bounds__(256)
concat_bias(const float* __restrict__ a, const float* __restrict__ b,
            const float* __restrict__ c, float* __restrict__ o)
{
    const int i = blockIdx.x * 256 + threadIdx.x;
    o[i] = (i < 512) ? a[i] : (i < 1024) ? b[i - 512] : c[i - 1024];
}

extern "C" void kernel_launch(void* const* d_in, const int* in_sizes, int n_in,
                              void* d_out, int out_size, void* d_ws, size_t ws_size,
                              hipStream_t stream)
{
    (void)in_sizes; (void)n_in; (void)out_size; (void)ws_size;

    const float* x = (const float*)d_in[0];
    const float* h = (const float*)d_in[1];
    const float* Wf[9]; const float* bia[9];
    for (int g = 0; g < 3; ++g)
        for (int j = 0; j < 3; ++j) {
            Wf[g * 3 + j]  = (const float*)d_in[2 + g * 6 + j * 2];
            bia[g * 3 + j] = (const float*)d_in[2 + g * 6 + j * 2 + 1];
        }
    const float* gamma = (const float*)d_in[20];
    const float* beta  = (const float*)d_in[21];
    float* out = (float*)d_out;

    const int LDS_BYTES = 131072;
    hipFuncSetAttribute((const void*)gemm256<EPI_QKV, 1>,  hipFuncAttributeMaxDynamicSharedMemorySize, LDS_BYTES);
    hipFuncSetAttribute((const void*)gemm256<EPI_PEXP, 0>, hipFuncAttributeMaxDynamicSharedMemorySize, LDS_BYTES);
    hipFuncSetAttribute((const void*)gemm256<EPI_R, 0>,    hipFuncAttributeMaxDynamicSharedMemorySize, LDS_BYTES);
    hipFuncSetAttribute((const void*)gemm256<EPI_Z, 0>,    hipFuncAttributeMaxDynamicSharedMemorySize, LDS_BYTES);
    hipFuncSetAttribute((const void*)gemm256<EPI_N, 0>,    hipFuncAttributeMaxDynamicSharedMemorySize, LDS_BYTES);

    char* ws = (char*)d_ws;
    size_t off = 0;
    auto alloc = [&](size_t bytes) -> void* {
        void* p = ws + off; off += (bytes + 255) & ~(size_t)255; return p;
    };
    unsigned short* xh  = (unsigned short*)alloc((size_t)32768 * 2048 * 2); // 134 MB
    unsigned short* WT  = (unsigned short*)alloc((size_t)12582912 * 2);     // 24 MB
    unsigned short* QK  = (unsigned short*)alloc((size_t)32768 * 1024 * 2); // 67 MB
    unsigned short* Vt  = (unsigned short*)alloc((size_t)32768 * 1024 * 2); // 67 MB
    unsigned short* Pb  = (unsigned short*)alloc((size_t)64 * 512 * 512 * 2);// 33.5 MB
    unsigned short* upd = (unsigned short*)alloc((size_t)32768 * 1024 * 2); // 67 MB
    float*          psb = (float*)alloc((size_t)2 * 32768 * 4);             // 256 KB
    float*          bct = (float*)alloc((size_t)3 * 2048 * 4);

    size_t wtoff[9];
    {
        size_t o = 0;
        for (int g = 0; g < 3; ++g) {
            wtoff[g * 3 + 0] = o; o += (size_t)512 * 2048;
            wtoff[g * 3 + 1] = o; o += (size_t)512 * 2048;
            wtoff[g * 3 + 2] = o; o += (size_t)1024 * 2048;
        }
    }

    prep_xh<<<32768, 256, 0, stream>>>(x, h, xh);
    for (int i = 0; i < 9; ++i) {
        const int N = (i % 3 == 2) ? 1024 : 512;
        transpose_w<<<dim3(N / 32, 64, 1), 256, 0, stream>>>(Wf[i], WT + wtoff[i], N);
    }
    for (int g = 0; g < 3; ++g)
        concat_bias<<<8, 256, 0, stream>>>(bia[g * 3 + 0], bia[g * 3 + 1], bia[g * 3 + 2], bct + g * 2048);

    const float scscale = 0.044194173824159216f; // 1/sqrt(512)

    auto gate = [&](int g, int epi) {
        const unsigned short* wT = WT + wtoff[g * 3 + 0];
        // fused QKV projection (N=2048): Q,K -> QK buffer; V -> Vt (transposed store)
        gemm256<EPI_QKV, 1><<<dim3(8, 128, 1), 512, LDS_BYTES, stream>>>(
            xh, 0, 2048, wT, 0, 2048, bct + g * 2048,
            QK, 0, 1024, 2048, 0.0f, nullptr, nullptr, nullptr, Vt);
        // P~ = exp(Q@K^T * scale) + per-row partial sums (batched over 64)
        gemm256<EPI_PEXP, 0><<<dim3(2, 2, 64), 512, LDS_BYTES, stream>>>(
            QK, 524288, 1024, QK + 512, 524288, 1024, nullptr,
            Pb, 262144, 512, 512, scscale, nullptr, nullptr, psb, nullptr);
        // PV (batched), rowsum-normalized, fused gate epilogue
        if (epi == EPI_Z)
            gemm256<EPI_Z, 0><<<dim3(4, 2, 64), 512, LDS_BYTES, stream>>>(
                Pb, 262144, 512, Vt, 524288, 512, nullptr,
                upd, 0, 1024, 512, 0.0f, nullptr, nullptr, psb, nullptr);
        else if (epi == EPI_R)
            gemm256<EPI_R, 0><<<dim3(4, 2, 64), 512, LDS_BYTES, stream>>>(
                Pb, 262144, 512, Vt, 524288, 512, nullptr,
                xh, 0, 2048, 512, 0.0f, h, nullptr, psb, nullptr);
        else
            gemm256<EPI_N, 0><<<dim3(4, 2, 64), 512, LDS_BYTES, stream>>>(
                Pb, 262144, 512, Vt, 524288, 512, nullptr,
                out, 0, 1024, 512, 0.0f, h, upd, psb, nullptr);
    };

    gate(1, EPI_Z);  // update = sigmoid(z-attn)            (reads original xh)
    gate(0, EPI_R);  // xh[:,1024:] = bf16(h * sigmoid(r))  (in-place -> xhr)
    gate(2, EPI_N);  // out = (1-u)*h + u*tanh(n-attn)
    layernorm1024<<<8192, 256, 0, stream>>>(out, gamma, beta);
}

// Round 9
// 1308.239 us; speedup vs baseline: 1.0110x; 1.0110x over previous
//
#include <hip/hip_runtime.h>
#include <math.h>

typedef __attribute__((ext_vector_type(8))) short short8;
typedef __attribute__((ext_vector_type(4))) float f32x4;

#define EPI_QKV   0
#define EPI_PEXP  1
#define EPI_R     2
#define EPI_Z     3
#define EPI_N     4

__device__ __forceinline__ unsigned short f2bf(float f) {
    unsigned int u = __float_as_uint(f);
    u += 0x7fffu + ((u >> 16) & 1u);
    return (unsigned short)(u >> 16);
}
__device__ __forceinline__ float bf2f(unsigned short s) {
    return __uint_as_float(((unsigned int)s) << 16);
}

struct alignas(8) us4 { unsigned short a, b, c, d; };

#define GLD_LDS16(gp, lp) \
    __builtin_amdgcn_global_load_lds((const __attribute__((address_space(1))) unsigned int*)(gp), \
                                     (__attribute__((address_space(3))) unsigned int*)(lp), 16, 0, 0)

#define BAR   do { asm volatile("" ::: "memory"); __builtin_amdgcn_s_barrier(); \
                   asm volatile("" ::: "memory"); } while (0)
#define VMC0  asm volatile("s_waitcnt vmcnt(0)" ::: "memory")

// ============================================================================
// 256x256 tile, BK=64, 512 threads (8 waves: 2M x 4N).
// SINGLE-BARRIER K-tile schedule (pure double buffer):
//   per tile t (read buf p=t&1, stage buf q=p^1):
//     STAGE tile t+1 -> q   (8 gload_lds, issued first for max HBM lead)
//     LDA(mh0,p) + LDB(all,p)  [16 ds_read_b128]
//     MMA q00, q01             [32 MFMA]
//     LDA(mh1,p)  (reuses a regs - reg dependency serializes correctly)
//     MMA q10, q11             [32 MFMA]
//     VMC0 (tile t+1 landed; issued ~2000cy earlier, cheap)  ; BAR
// Hazard proof:
//   WAR (stage q vs prev reads of q): a wave reaches BAR only after ALL its
//     ds_reads were consumed by MFMA issue (operands) -> retired. Stage of
//     tile t+1 into q issues after BAR(t) -> no overlap with t-1's q-reads.
//   RAW (stage -> read): VMC0 before BAR; reads after BAR. Cross-wave safe.
//   In-wave reg reuse (a): compiler orders LDA(mh1) after MMA(mh0) issue.
// 1 barrier + 1 vmcnt per K-tile (round 6 had 5 + 3).
// LDS 128 KiB, XOR-swizzle byte^=(row&7)<<4 via inverse-swizzled global src.
// ============================================================================
template<int EPI, int SWZ>
__global__ void __launch_bounds__(512, 2)
gemm256(const unsigned short* __restrict__ A, long long sAb, int lda,
        const unsigned short* __restrict__ Bt, long long sBb, int ldb,
        const float* __restrict__ bias,
        void* __restrict__ C, long long sCb, int ldc,
        int K, float scale,
        const float* __restrict__ hptr,
        const unsigned short* __restrict__ updptr,
        float* __restrict__ psum,
        unsigned short* __restrict__ vt)
{
    extern __shared__ char smem[];   // 131072 B

    const int z = blockIdx.z;
    A  += (size_t)z * (size_t)sAb;
    Bt += (size_t)z * (size_t)sBb;

    int bx, by;
    if (SWZ) {
        const int bid = blockIdx.y * 8 + blockIdx.x;   // grid (8,128)
        const int xcd = bid & 7, i = bid >> 3;
        bx = i & 7;
        by = (xcd << 4) | (i >> 3);
    } else {
        bx = blockIdx.x; by = blockIdx.y;
    }
    const int m0 = by * 256;
    const int n0 = bx * 256;

    const int tid = threadIdx.x;
    const int w  = tid >> 6;      // wave 0..7
    const int l  = tid & 63;
    const int wr = w >> 2;        // 0..1 (M half: 128 rows)
    const int wc = w & 3;         // 0..3 (N quarter: 64 cols)
    const int lr = l & 15;
    const int lg = l >> 4;
    const int rs = (lr & 7) << 4; // read-side XOR swizzle

    const int srw = l >> 3;                        // staging row-within-8
    const int scb = ((l & 7) << 4) ^ (srw << 4);   // inverse-swizzled src col byte

    const long long ldab = (long long)lda * 2;
    const long long ldbb = (long long)ldb * 2;

    f32x4 acc[2][4][4] = {};
    short8 a[4][2], b[4][2];

#define STAGE1(gbase, ldbytes, grow0, ldsoff) { \
    const char* g_ = (const char*)(gbase) + \
        (size_t)((grow0) + w*8 + srw) * (ldbytes) + scb; \
    GLD_LDS16(g_, smem + (ldsoff) + (w << 10)); }

#define AOFF(buf) ((buf)*65536)
#define BOFF(buf) ((buf)*65536 + 32768)

// stage a full 256x64 operand tile into a buffer (4 STAGE1 = 4 gload_lds/thread)
#define SA(buf, base) { STAGE1(base, ldab, m0 + 0,   AOFF(buf) + 0); \
                        STAGE1(base, ldab, m0 + 64,  AOFF(buf) + 8192); \
                        STAGE1(base, ldab, m0 + 128, AOFF(buf) + 16384); \
                        STAGE1(base, ldab, m0 + 192, AOFF(buf) + 24576); }
#define SB(buf, base) { STAGE1(base, ldbb, n0 + 0,   BOFF(buf) + 0); \
                        STAGE1(base, ldbb, n0 + 64,  BOFF(buf) + 8192); \
                        STAGE1(base, ldbb, n0 + 128, BOFF(buf) + 16384); \
                        STAGE1(base, ldbb, n0 + 192, BOFF(buf) + 24576); }

// register loads (8 / 4 x ds_read_b128)
#define LDA8(MH, buf) { \
    const char* Ab_ = smem + AOFF(buf); \
    _Pragma("unroll") \
    for (int mf = 0; mf < 4; ++mf) { \
        const int row_ = wr*128 + (MH)*64 + mf*16 + lr; \
        _Pragma("unroll") \
        for (int kk = 0; kk < 2; ++kk) \
            a[mf][kk] = *(const short8*)(Ab_ + row_*128 + ((kk*64 + lg*16) ^ rs)); } }

#define LDB4(BH, buf) { \
    const char* Bb_ = smem + BOFF(buf); \
    _Pragma("unroll") \
    for (int nf = 0; nf < 2; ++nf) { \
        const int row_ = wc*64 + (BH)*32 + nf*16 + lr; \
        _Pragma("unroll") \
        for (int kk = 0; kk < 2; ++kk) \
            b[(BH)*2+nf][kk] = *(const short8*)(Bb_ + row_*128 + ((kk*64 + lg*16) ^ rs)); } }

// one C-quadrant x K=64: 16 MFMA, kk outer (dep distance 8)
#define MMA16(MH, BH) { \
    __builtin_amdgcn_s_setprio(1); \
    _Pragma("unroll") \
    for (int kk = 0; kk < 2; ++kk) \
    _Pragma("unroll") \
    for (int mf = 0; mf < 4; ++mf) \
    _Pragma("unroll") \
    for (int nf = 0; nf < 2; ++nf) \
        acc[MH][mf][(BH)*2+nf] = __builtin_amdgcn_mfma_f32_16x16x32_bf16( \
            a[mf][kk], b[(BH)*2+nf][kk], acc[MH][mf][(BH)*2+nf], 0, 0, 0); \
    __builtin_amdgcn_s_setprio(0); }

    // prologue: stage tile0 -> buf0
    SA(0, A); SB(0, Bt);
    VMC0;
    BAR;

    const int NT = K >> 6;
    for (int t = 0; t < NT; ++t) {
        const int p = t & 1, q = p ^ 1;
        const bool s1 = (t + 1 < NT);
        const unsigned short* Anx = A  + (size_t)(t + 1) * 64;
        const unsigned short* Bnx = Bt + (size_t)(t + 1) * 64;

        if (s1) { SA(q, Anx); SB(q, Bnx); }      // 8 gload_lds, earliest issue
        LDA8(0, p); LDB4(0, p); LDB4(1, p);      // 16 ds_read_b128
        MMA16(0, 0); MMA16(0, 1);                // 32 MFMA
        LDA8(1, p);                              // 8 ds_read_b128 (reuse a)
        MMA16(1, 0); MMA16(1, 1);                // 32 MFMA
        VMC0;                                    // tile t+1 landed
        BAR;
    }

    // ======================= epilogues =======================
    const int Mb = gridDim.y << 8;          // rows per batch slab
    const size_t zc = (size_t)z * (size_t)sCb;

    if (EPI == EPI_PEXP) {
        float psl[2][4][4];
        #pragma unroll
        for (int mh = 0; mh < 2; ++mh)
            #pragma unroll
            for (int mf = 0; mf < 4; ++mf)
                #pragma unroll
                for (int r = 0; r < 4; ++r) psl[mh][mf][r] = 0.0f;

        #pragma unroll
        for (int mh = 0; mh < 2; ++mh)
        #pragma unroll
        for (int mf = 0; mf < 4; ++mf)
        #pragma unroll
        for (int nf = 0; nf < 4; ++nf) {
            const int col = n0 + wc * 64 + nf * 16 + lr;
            #pragma unroll
            for (int r = 0; r < 4; ++r) {
                const int row = m0 + wr * 128 + mh * 64 + mf * 16 + lg * 4 + r;
                const float e = __expf(acc[mh][mf][nf][r] * scale);
                ((unsigned short*)C)[zc + (size_t)row * ldc + col] = f2bf(e);
                psl[mh][mf][r] += e;
            }
        }
        #pragma unroll
        for (int d = 1; d < 16; d <<= 1)
            #pragma unroll
            for (int mh = 0; mh < 2; ++mh)
                #pragma unroll
                for (int mf = 0; mf < 4; ++mf)
                    #pragma unroll
                    for (int r = 0; r < 4; ++r)
                        psl[mh][mf][r] += __shfl_xor(psl[mh][mf][r], d);
        __syncthreads();
        float* red = (float*)smem;             // [4 waves][256 rows]
        if (lr == 0) {
            #pragma unroll
            for (int mh = 0; mh < 2; ++mh)
                #pragma unroll
                for (int mf = 0; mf < 4; ++mf)
                    #pragma unroll
                    for (int r = 0; r < 4; ++r)
                        red[wc * 256 + wr * 128 + mh * 64 + mf * 16 + lg * 4 + r]
                            = psl[mh][mf][r];
        }
        __syncthreads();
        if (tid < 256) {
            const float sres = red[tid] + red[256 + tid] + red[512 + tid] + red[768 + tid];
            psum[(size_t)bx * 32768 + (size_t)z * 512 + m0 + tid] = sres;
        }
        return;
    }

    float invs[2][4][4];
    if (EPI == EPI_R || EPI == EPI_Z || EPI == EPI_N) {
        #pragma unroll
        for (int mh = 0; mh < 2; ++mh)
            #pragma unroll
            for (int mf = 0; mf < 4; ++mf)
                #pragma unroll
                for (int r = 0; r < 4; ++r) {
                    const int row = m0 + wr * 128 + mh * 64 + mf * 16 + lg * 4 + r;
                    const size_t gr = (size_t)z * 512 + row;
                    invs[mh][mf][r] = 1.0f / (psum[gr] + psum[32768 + gr]);
                }
    }

    #pragma unroll
    for (int mh = 0; mh < 2; ++mh) {
        #pragma unroll
        for (int mf = 0; mf < 4; ++mf) {
            #pragma unroll
            for (int nf = 0; nf < 4; ++nf) {
                const int col = n0 + wc * 64 + nf * 16 + lr;
                const float bval = (EPI == EPI_QKV) ? bias[col] : 0.0f;
                if (EPI == EPI_QKV && bx >= 4) {
                    const int row0 = m0 + wr * 128 + mh * 64 + mf * 16 + lg * 4;
                    us4 o = { f2bf(acc[mh][mf][nf][0] + bval),
                              f2bf(acc[mh][mf][nf][1] + bval),
                              f2bf(acc[mh][mf][nf][2] + bval),
                              f2bf(acc[mh][mf][nf][3] + bval) };
                    *(us4*)(vt + (size_t)(row0 >> 9) * 524288 +
                            (size_t)(col - 1024) * 512 + (row0 & 511)) = o;
                } else {
                    #pragma unroll
                    for (int r = 0; r < 4; ++r) {
                        const int row = m0 + wr * 128 + mh * 64 + mf * 16 + lg * 4 + r;
                        float v = acc[mh][mf][nf][r] + bval;
                        if (EPI == EPI_QKV) {
                            ((unsigned short*)C)[(size_t)row * ldc + col] = f2bf(v);
                        } else if (EPI == EPI_R) {
                            v *= invs[mh][mf][r];
                            const size_t flat = (size_t)z * Mb + row;
                            const float hh = hptr[flat * 1024 + col];
                            const float sg = 1.0f / (1.0f + __expf(-v));
                            ((unsigned short*)C)[flat * 2048 + 1024 + col] = f2bf(hh * sg);
                        } else if (EPI == EPI_Z) {
                            v *= invs[mh][mf][r];
                            const size_t flat = (size_t)z * Mb + row;
                            const float sg = 1.0f / (1.0f + __expf(-v));
                            ((unsigned short*)C)[flat * 1024 + col] = f2bf(sg);
                        } else { // EPI_N
                            v *= invs[mh][mf][r];
                            const size_t flat = (size_t)z * Mb + row;
                            const float u  = bf2f(updptr[flat * 1024 + col]);
                            const float hh = hptr[flat * 1024 + col];
                            ((float*)C)[flat * 1024 + col] = (1.0f - u) * hh + u * tanhf(v);
                        }
                    }
                }
            }
        }
    }
#undef STAGE1
#undef AOFF
#undef BOFF
#undef SA
#undef SB
#undef LDA8
#undef LDB4
#undef MMA16
}

// ============================================================================
// memory-bound helper kernels
// ============================================================================

__global__ void __launch_bounds__(256)
prep_xh(const float* __restrict__ x, const float* __restrict__ h, unsigned short* __restrict__ xh)
{
    const size_t t = (size_t)blockIdx.x * 256 + threadIdx.x;
    const size_t f = t * 4;
    const size_t row = f >> 10, col = f & 1023;
    const float4 vx = *(const float4*)(x + f);
    const float4 vh = *(const float4*)(h + f);
    us4 ox = { f2bf(vx.x), f2bf(vx.y), f2bf(vx.z), f2bf(vx.w) };
    us4 oh = { f2bf(vh.x), f2bf(vh.y), f2bf(vh.z), f2bf(vh.w) };
    *(us4*)(xh + row * 2048 + col)        = ox;
    *(us4*)(xh + row * 2048 + 1024 + col) = oh;
}

__global__ void __launch_bounds__(256)
transpose_w(const float* __restrict__ W, unsigned short* __restrict__ WT, int N)
{
    __shared__ float t[32][33];
    const int k0 = blockIdx.y * 32, n0 = blockIdx.x * 32;
    const int tx = threadIdx.x & 31, ty = threadIdx.x >> 5;
    #pragma unroll
    for (int i = 0; i < 4; ++i)
        t[ty + i * 8][tx] = W[(size_t)(k0 + ty + i * 8) * N + n0 + tx];
    __syncthreads();
    #pragma unroll
    for (int i = 0; i < 4; ++i)
        WT[(size_t)(n0 + ty + i * 8) * 2048 + k0 + tx] = f2bf(t[tx][ty + i * 8]);
}

__global__ void __launch_bounds__(256)
layernorm1024(float* __restrict__ Y, const float* __restrict__ gamma, const float* __restrict__ beta)
{
    const int row = blockIdx.x * 4 + (threadIdx.x >> 6);
    const int l = threadIdx.x & 63;
    float* p = Y + (size_t)row * 1024;
    float4 v[4];
    float s = 0.0f, s2 = 0.0f;
    #pragma unroll
    for (int i = 0; i < 4; ++i) {
        v[i] = ((const float4*)p)[i * 64 + l];
        s  += v[i].x + v[i].y + v[i].z + v[i].w;
        s2 += v[i].x * v[i].x + v[i].y * v[i].y + v[i].z * v[i].z + v[i].w * v[i].w;
    }
    #pragma unroll
    for (int d = 32; d; d >>= 1) { s += __shfl_xor(s, d); s2 += __shfl_xor(s2, d); }
    const float mu = s * (1.0f / 1024.0f);
    const float var = s2 * (1.0f / 1024.0f) - mu * mu;
    const float inv = rsqrtf(var + 1e-5f);
    #pragma unroll
    for (int i = 0; i < 4; ++i) {
        const float4 gv = ((const float4*)gamma)[i * 64 + l];
        const float4 bv = ((const float4*)beta)[i * 64 + l];
        float4 o;
        o.x = (v[i].x - mu) * inv * gv.x + bv.x;
        o.y = (v[i].y - mu) * inv * gv.y + bv.y;
        o.z = (v[i].z - mu) * inv * gv.z + bv.z;
        o.w = (v[i].w - mu) * inv * gv.w + bv.w;
        ((float4*)p)[i * 64 + l] = o;
    }
}

__global__ void __launch_bounds__(256)
concat_bias(const float* __restrict__ a, const float* __restrict__ b,
            const float* __restrict__ c, float* __restrict__ o)
{
    const int i = blockIdx.x * 256 + threadIdx.x;
    o[i] = (i < 512) ? a[i] : (i < 1024) ? b[i - 512] : c[i - 1024];
}

extern "C" void kernel_launch(void* const* d_in, const int* in_sizes, int n_in,
                              void* d_out, int out_size, void* d_ws, size_t ws_size,
                              hipStream_t stream)
{
    (void)in_sizes; (void)n_in; (void)out_size; (void)ws_size;

    const float* x = (const float*)d_in[0];
    const float* h = (const float*)d_in[1];
    const float* Wf[9]; const float* bia[9];
    for (int g = 0; g < 3; ++g)
        for (int j = 0; j < 3; ++j) {
            Wf[g * 3 + j]  = (const float*)d_in[2 + g * 6 + j * 2];
            bia[g * 3 + j] = (const float*)d_in[2 + g * 6 + j * 2 + 1];
        }
    const float* gamma = (const float*)d_in[20];
    const float* beta  = (const float*)d_in[21];
    float* out = (float*)d_out;

    const int LDS_BYTES = 131072;
    hipFuncSetAttribute((const void*)gemm256<EPI_QKV, 1>,  hipFuncAttributeMaxDynamicSharedMemorySize, LDS_BYTES);
    hipFuncSetAttribute((const void*)gemm256<EPI_PEXP, 0>, hipFuncAttributeMaxDynamicSharedMemorySize, LDS_BYTES);
    hipFuncSetAttribute((const void*)gemm256<EPI_R, 0>,    hipFuncAttributeMaxDynamicSharedMemorySize, LDS_BYTES);
    hipFuncSetAttribute((const void*)gemm256<EPI_Z, 0>,    hipFuncAttributeMaxDynamicSharedMemorySize, LDS_BYTES);
    hipFuncSetAttribute((const void*)gemm256<EPI_N, 0>,    hipFuncAttributeMaxDynamicSharedMemorySize, LDS_BYTES);

    char* ws = (char*)d_ws;
    size_t off = 0;
    auto alloc = [&](size_t bytes) -> void* {
        void* p = ws + off; off += (bytes + 255) & ~(size_t)255; return p;
    };
    unsigned short* xh  = (unsigned short*)alloc((size_t)32768 * 2048 * 2); // 134 MB
    unsigned short* WT  = (unsigned short*)alloc((size_t)12582912 * 2);     // 24 MB
    unsigned short* QK  = (unsigned short*)alloc((size_t)32768 * 1024 * 2); // 67 MB
    unsigned short* Vt  = (unsigned short*)alloc((size_t)32768 * 1024 * 2); // 67 MB
    unsigned short* Pb  = (unsigned short*)alloc((size_t)64 * 512 * 512 * 2);// 33.5 MB
    unsigned short* upd = (unsigned short*)alloc((size_t)32768 * 1024 * 2); // 67 MB
    float*          psb = (float*)alloc((size_t)2 * 32768 * 4);             // 256 KB
    float*          bct = (float*)alloc((size_t)3 * 2048 * 4);

    size_t wtoff[9];
    {
        size_t o = 0;
        for (int g = 0; g < 3; ++g) {
            wtoff[g * 3 + 0] = o; o += (size_t)512 * 2048;
            wtoff[g * 3 + 1] = o; o += (size_t)512 * 2048;
            wtoff[g * 3 + 2] = o; o += (size_t)1024 * 2048;
        }
    }

    prep_xh<<<32768, 256, 0, stream>>>(x, h, xh);
    for (int i = 0; i < 9; ++i) {
        const int N = (i % 3 == 2) ? 1024 : 512;
        transpose_w<<<dim3(N / 32, 64, 1), 256, 0, stream>>>(Wf[i], WT + wtoff[i], N);
    }
    for (int g = 0; g < 3; ++g)
        concat_bias<<<8, 256, 0, stream>>>(bia[g * 3 + 0], bia[g * 3 + 1], bia[g * 3 + 2], bct + g * 2048);

    const float scscale = 0.044194173824159216f; // 1/sqrt(512)

    auto gate = [&](int g, int epi) {
        const unsigned short* wT = WT + wtoff[g * 3 + 0];
        // fused QKV projection (N=2048): Q,K -> QK buffer; V -> Vt (transposed store)
        gemm256<EPI_QKV, 1><<<dim3(8, 128, 1), 512, LDS_BYTES, stream>>>(
            xh, 0, 2048, wT, 0, 2048, bct + g * 2048,
            QK, 0, 1024, 2048, 0.0f, nullptr, nullptr, nullptr, Vt);
        // P~ = exp(Q@K^T * scale) + per-row partial sums (batched over 64)
        gemm256<EPI_PEXP, 0><<<dim3(2, 2, 64), 512, LDS_BYTES, stream>>>(
            QK, 524288, 1024, QK + 512, 524288, 1024, nullptr,
            Pb, 262144, 512, 512, scscale, nullptr, nullptr, psb, nullptr);
        // PV (batched), rowsum-normalized, fused gate epilogue
        if (epi == EPI_Z)
            gemm256<EPI_Z, 0><<<dim3(4, 2, 64), 512, LDS_BYTES, stream>>>(
                Pb, 262144, 512, Vt, 524288, 512, nullptr,
                upd, 0, 1024, 512, 0.0f, nullptr, nullptr, psb, nullptr);
        else if (epi == EPI_R)
            gemm256<EPI_R, 0><<<dim3(4, 2, 64), 512, LDS_BYTES, stream>>>(
                Pb, 262144, 512, Vt, 524288, 512, nullptr,
                xh, 0, 2048, 512, 0.0f, h, nullptr, psb, nullptr);
        else
            gemm256<EPI_N, 0><<<dim3(4, 2, 64), 512, LDS_BYTES, stream>>>(
                Pb, 262144, 512, Vt, 524288, 512, nullptr,
                out, 0, 1024, 512, 0.0f, h, upd, psb, nullptr);
    };

    gate(1, EPI_Z);  // update = sigmoid(z-attn)            (reads original xh)
    gate(0, EPI_R);  // xh[:,1024:] = bf16(h * sigmoid(r))  (in-place -> xhr)
    gate(2, EPI_N);  // out = (1-u)*h + u*tanh(n-attn)
    layernorm1024<<<8192, 256, 0, stream>>>(out, gamma, beta);
}